// Round 1
// baseline (565.905 us; speedup 1.0000x reference)
//
#include <hip/hip_runtime.h>
#include <hip/hip_bf16.h>

// hierarch_sep_loss: preds [2, N, 100] fp32 probs, labs [2, N] int, cen [2, N] int
// out[0] = sum over mods of:
//   (n_u/N) * (-sum_{cen==0} log(p[i,lab_i]+EPS) / max(1,n_u))
// + (n_c/N) * (-sum_{cen==1} log(sum_{j>lab0_i} p[i,j]+EPS) / max(1,n_c)) * 0.5
//
// R6 post-mortem: minimal-bytes gather structure plateaus at ~2.9 TB/s
// (scattered 64-192B requests, sector over-fetch on 16B-aligned 400B rows).
// R7: FULL STREAM instead. Each 4-lane group reads its whole row via 25
// aligned float4s (lane q takes f4 = 4k+q); every fetched line is fully
// consumed, a wave covers a contiguous 6.4KB span. Per row, one branchless
// masked sum over an index range [lo,hi]:
//   uncensored: lo=hi=lab            (the gather)
//   censored:   lo=t1, hi=99         (direct suffix sum — no 1-prefix trick,
//                                     so no cancellation; t1=100 -> empty -> 0)
// 412 MB total @ ~6 TB/s streaming => ~70us vs ~140-230us for the gather.

#define HSL_EPS 1e-10f
#define NBLK 2048

__global__ __launch_bounds__(256, 8) void hsl_main(
    const float* __restrict__ preds,
    const int*   __restrict__ labs,
    const int*   __restrict__ cen,
    double*       __restrict__ bsums,  // [4][NBLK] per-block partials
    unsigned int* __restrict__ bcnts,  // [4][NBLK]
    long long N)
{
    const long long R = 2LL * N;
    const int q = threadIdx.x & 3;               // lane within 4-lane row group
    const long long g0 = ((long long)blockIdx.x * blockDim.x + threadIdx.x) >> 2;
    const long long ng = ((long long)gridDim.x * blockDim.x) >> 2;

    double usum[2] = {0.0, 0.0};
    double csum[2] = {0.0, 0.0};
    unsigned int ucnt[2] = {0u, 0u};
    unsigned int ccnt[2] = {0u, 0u};

    for (long long r = g0; r < R; r += ng) {
        const int m = (r >= N) ? 1 : 0;
        const long long i0 = r - (long long)m * N;
        const int c   = cen[r];
        const int lab = labs[r];
        const int t1  = labs[i0] + 1;            // censored: sum over j >= t1, t1 in [1,100]

        // branchless per-row target range [lo,hi]
        const int lo = (c == 0) ? lab : t1;
        const int hi = (c == 0) ? lab : 99;

        const float4* rowp4 = (const float4*)(preds + r * 100);

        // ---- stream the whole row: 25 float4s, lane q reads f4 = 4k+q ----
        float acc = 0.0f;
        #pragma unroll
        for (int k = 0; k < 7; ++k) {
            const int f4 = 4 * k + q;
            if (f4 < 25) {                       // only lane 0 takes k==6 fully
                const float4 v = rowp4[f4];
                const int j0 = 4 * f4;
                #pragma unroll
                for (int e = 0; e < 4; ++e) {
                    const int j = j0 + e;
                    const float p = ((const float*)&v)[e];
                    acc += (j >= lo && j <= hi) ? p : 0.0f;
                }
            }
        }

        // reduce 4 partials within the group
        acc += __shfl_xor(acc, 1, 64);
        acc += __shfl_xor(acc, 2, 64);

        if (q == 0) {
            const double lg = (double)logf(acc + HSL_EPS);
            if (c == 0) { usum[m] += lg; ucnt[m]++; }
            else        { csum[m] += lg; ccnt[m]++; }
        }
    }

    // ---- wave shuffle reduction -> block LDS -> one plain store per block ----
    #pragma unroll
    for (int off = 32; off > 0; off >>= 1) {
        usum[0] += __shfl_down(usum[0], off, 64);
        csum[0] += __shfl_down(csum[0], off, 64);
        usum[1] += __shfl_down(usum[1], off, 64);
        csum[1] += __shfl_down(csum[1], off, 64);
        ucnt[0] += __shfl_down(ucnt[0], off, 64);
        ccnt[0] += __shfl_down(ccnt[0], off, 64);
        ucnt[1] += __shfl_down(ucnt[1], off, 64);
        ccnt[1] += __shfl_down(ccnt[1], off, 64);
    }

    __shared__ double sh_sums[4][4];
    __shared__ unsigned int sh_cnts[4][4];
    const int waveInBlk = threadIdx.x >> 6;
    const int lane = threadIdx.x & 63;
    if (lane == 0) {
        sh_sums[waveInBlk][0] = usum[0]; sh_sums[waveInBlk][1] = csum[0];
        sh_sums[waveInBlk][2] = usum[1]; sh_sums[waveInBlk][3] = csum[1];
        sh_cnts[waveInBlk][0] = ucnt[0]; sh_cnts[waveInBlk][1] = ccnt[0];
        sh_cnts[waveInBlk][2] = ucnt[1]; sh_cnts[waveInBlk][3] = ccnt[1];
    }
    __syncthreads();
    if (threadIdx.x < 4) {
        const int slot = threadIdx.x;
        double s = 0.0; unsigned int k = 0u;
        for (int w = 0; w < 4; ++w) { s += sh_sums[w][slot]; k += sh_cnts[w][slot]; }
        bsums[slot * NBLK + blockIdx.x] = s;
        bcnts[slot * NBLK + blockIdx.x] = k;
    }
}

__global__ __launch_bounds__(256) void hsl_final(
    const double* __restrict__ bsums,
    const unsigned int* __restrict__ bcnts,
    float* __restrict__ out, long long N, int nblk)
{
    double s[4] = {0.0, 0.0, 0.0, 0.0};
    double kc[4] = {0.0, 0.0, 0.0, 0.0};
    for (int b = threadIdx.x; b < nblk; b += 256) {
        #pragma unroll
        for (int slot = 0; slot < 4; ++slot) {
            s[slot]  += bsums[slot * nblk + b];
            kc[slot] += (double)bcnts[slot * nblk + b];
        }
    }

    #pragma unroll
    for (int off = 32; off > 0; off >>= 1) {
        #pragma unroll
        for (int slot = 0; slot < 4; ++slot) {
            s[slot]  += __shfl_down(s[slot],  off, 64);
            kc[slot] += __shfl_down(kc[slot], off, 64);
        }
    }

    __shared__ double sh[4][8];
    const int waveInBlk = threadIdx.x >> 6;
    const int lane = threadIdx.x & 63;
    if (lane == 0) {
        #pragma unroll
        for (int slot = 0; slot < 4; ++slot) {
            sh[waveInBlk][slot]     = s[slot];
            sh[waveInBlk][4 + slot] = kc[slot];
        }
    }
    __syncthreads();
    if (threadIdx.x == 0) {
        double fs[4], fk[4];
        #pragma unroll
        for (int slot = 0; slot < 4; ++slot) {
            fs[slot] = sh[0][slot] + sh[1][slot] + sh[2][slot] + sh[3][slot];
            fk[slot] = sh[0][4+slot] + sh[1][4+slot] + sh[2][4+slot] + sh[3][4+slot];
        }
        float total = 0.0f;
        const float n = (float)N;
        for (int m = 0; m < 2; ++m) {
            const float nu = (float)fk[2 * m + 0];
            const float nc = (float)fk[2 * m + 1];
            const float us = (float)fs[2 * m + 0];
            const float cs = (float)fs[2 * m + 1];
            const float uncen_loss = -us / fmaxf(1.0f, nu);
            const float cen_loss   = -cs / fmaxf(1.0f, nc);
            total += (nu / n) * uncen_loss + (nc / n) * cen_loss * 0.5f;
        }
        out[0] = total;
    }
}

extern "C" void kernel_launch(void* const* d_in, const int* in_sizes, int n_in,
                              void* d_out, int out_size, void* d_ws, size_t ws_size,
                              hipStream_t stream)
{
    const float* preds = (const float*)d_in[0];
    const int*   labs  = (const int*)d_in[1];
    const int*   cen   = (const int*)d_in[2];
    float* out = (float*)d_out;

    const long long N = (long long)(in_sizes[1] / 2);   // labs flat = 2*N; B=100 hardcoded

    double*       bsums = (double*)d_ws;
    unsigned int* bcnts = (unsigned int*)((char*)d_ws + (size_t)4 * NBLK * sizeof(double));

    hsl_main<<<NBLK, 256, 0, stream>>>(preds, labs, cen, bsums, bcnts, N);
    hsl_final<<<1, 256, 0, stream>>>(bsums, bcnts, out, N, NBLK);
}

// Round 2
// 481.641 us; speedup vs baseline: 1.1750x; 1.1750x over previous
//
#include <hip/hip_runtime.h>
#include <hip/hip_bf16.h>

// hierarch_sep_loss: preds [2, N, 100] fp32 probs, labs [2, N] int, cen [2, N] int
// out[0] = sum over mods of:
//   (n_u/N) * (-sum_{cen==0} log(p[i,lab_i]+EPS) / max(1,n_u))
// + (n_c/N) * (-sum_{cen==1} log(sum_{j>lab0_i} p[i,j]+EPS) / max(1,n_c)) * 0.5
//
// R7 post-mortem: full-stream regressed (+85us) — marginal read rate ~2.8 TB/s,
// so MORE bytes at the same rate loses. R6's gather is latency-bound, not
// BW-bound (~230us vs ~20-40us traffic floor): per row a serial labs->preds
// dependent chain with only 1 row in flight per group.
// R8: batch-4 pipeline, minimal traffic kept.
//  - group g owns rows 4g..4g+3 per batch; lane q loads descriptors for row
//    4g+q -> wave reads 64 consecutive ints per array (1 coalesced wait).
//  - all 4 rows' preds loads then issue concurrently: own-lane uncensored
//    gather (1 instr / 4 rows) + cooperative predicated prefix/suffix sums
//    for censored rows, unrolled over j (independent -> deep MLP).
//  - mod-0 lanes reuse labs[r] as labs0[i0] (i0==r), skipping one load.
//  - only 2 batch iterations per group -> ~2 latency exposures total.

#define HSL_EPS 1e-10f
#define NBLK 2048

__global__ __launch_bounds__(256, 4) void hsl_main(
    const float* __restrict__ preds,
    const int*   __restrict__ labs,
    const int*   __restrict__ cen,
    double*       __restrict__ bsums,  // [4][NBLK] per-block partials
    unsigned int* __restrict__ bcnts,  // [4][NBLK]
    long long N)
{
    const long long R = 2LL * N;
    const int q = threadIdx.x & 3;               // lane within 4-lane row group
    const long long g0 = ((long long)blockIdx.x * blockDim.x + threadIdx.x) >> 2;
    const long long ng = ((long long)gridDim.x * blockDim.x) >> 2;

    double usum[2] = {0.0, 0.0};
    double csum[2] = {0.0, 0.0};
    unsigned int ucnt[2] = {0u, 0u};
    unsigned int ccnt[2] = {0u, 0u};

    for (long long rb = 4 * g0; rb < R; rb += 4 * ng) {
        const long long myrow = rb + q;          // lane's own row
        const bool valid = (myrow < R);
        const long long rowc = valid ? myrow : (R - 1);   // clamped (safe reads)

        // ---- coalesced descriptor loads: 64 consecutive ints per wave ----
        const int my_m   = (rowc >= N) ? 1 : 0;
        const long long i0 = rowc - (long long)my_m * N;
        const int my_c   = cen[rowc];
        const int my_lab = labs[rowc];
        // mod 0: i0 == rowc, so labs0 value == my_lab (skip second load)
        const int my_t1  = (my_m ? labs[i0] : my_lab) + 1;   // in [1,100]

        // ---- own-row uncensored gather: ONE instr covers all 4 rows ----
        if (valid && my_c == 0) {
            const float gp = preds[rowc * 100 + my_lab];
            usum[my_m] += (double)logf(gp + HSL_EPS);
            ucnt[my_m]++;
        }

        // ---- censored rows: cooperative predicated prefix/suffix sums,
        //      unrolled over j -> all rows' loads independent & in flight ----
        #pragma unroll
        for (int j = 0; j < 4; ++j) {
            const int c_j = __shfl(my_c, j, 4);
            if (c_j != 1) continue;              // group-uniform skip
            const int t1_j = __shfl(my_t1, j, 4);
            const long long r_j = (long long)__shfl((float)0, 0, 4) * 0 + (rb + j); // rb+j; clamped below
            const long long rj = (r_j < R) ? r_j : (R - 1);

            const bool pre = (t1_j <= 50);
            const int b4 = pre ? 0 : (t1_j >> 2);    // starting float4 index
            const float4* rowp4 = (const float4*)(preds + rj * 100);

            float sp = 0.0f;
            #pragma unroll
            for (int k = 0; k < 4; ++k) {
                const int f4 = b4 + 4 * k + q;
                const bool issue = pre ? (4 * f4 < t1_j) : (f4 <= 24);
                if (issue) {                     // masked lanes: no mem request
                    const float4 v = rowp4[f4];
                    #pragma unroll
                    for (int e = 0; e < 4; ++e) {
                        const int jj = 4 * f4 + e;
                        const float p = ((const float*)&v)[e];
                        const bool use = pre ? (jj < t1_j) : (jj >= t1_j);
                        sp += use ? p : 0.0f;
                    }
                }
            }
            // reduce 4 quarter-partials within the group
            sp += __shfl_xor(sp, 1, 64);
            sp += __shfl_xor(sp, 2, 64);
            if (q == j && valid) {               // owner lane: my_m == m_j
                const float s = pre ? (1.0f - sp) : sp;
                csum[my_m] += (double)logf(s + HSL_EPS);
                ccnt[my_m]++;
            }
        }
    }

    // ---- wave shuffle reduction -> block LDS -> one plain store per block ----
    #pragma unroll
    for (int off = 32; off > 0; off >>= 1) {
        usum[0] += __shfl_down(usum[0], off, 64);
        csum[0] += __shfl_down(csum[0], off, 64);
        usum[1] += __shfl_down(usum[1], off, 64);
        csum[1] += __shfl_down(csum[1], off, 64);
        ucnt[0] += __shfl_down(ucnt[0], off, 64);
        ccnt[0] += __shfl_down(ccnt[0], off, 64);
        ucnt[1] += __shfl_down(ucnt[1], off, 64);
        ccnt[1] += __shfl_down(ccnt[1], off, 64);
    }

    __shared__ double sh_sums[4][4];
    __shared__ unsigned int sh_cnts[4][4];
    const int waveInBlk = threadIdx.x >> 6;
    const int lane = threadIdx.x & 63;
    if (lane == 0) {
        sh_sums[waveInBlk][0] = usum[0]; sh_sums[waveInBlk][1] = csum[0];
        sh_sums[waveInBlk][2] = usum[1]; sh_sums[waveInBlk][3] = csum[1];
        sh_cnts[waveInBlk][0] = ucnt[0]; sh_cnts[waveInBlk][1] = ccnt[0];
        sh_cnts[waveInBlk][2] = ucnt[1]; sh_cnts[waveInBlk][3] = ccnt[1];
    }
    __syncthreads();
    if (threadIdx.x < 4) {
        const int slot = threadIdx.x;
        double s = 0.0; unsigned int k = 0u;
        for (int w = 0; w < 4; ++w) { s += sh_sums[w][slot]; k += sh_cnts[w][slot]; }
        bsums[slot * NBLK + blockIdx.x] = s;
        bcnts[slot * NBLK + blockIdx.x] = k;
    }
}

__global__ __launch_bounds__(256) void hsl_final(
    const double* __restrict__ bsums,
    const unsigned int* __restrict__ bcnts,
    float* __restrict__ out, long long N, int nblk)
{
    double s[4] = {0.0, 0.0, 0.0, 0.0};
    double kc[4] = {0.0, 0.0, 0.0, 0.0};
    for (int b = threadIdx.x; b < nblk; b += 256) {
        #pragma unroll
        for (int slot = 0; slot < 4; ++slot) {
            s[slot]  += bsums[slot * nblk + b];
            kc[slot] += (double)bcnts[slot * nblk + b];
        }
    }

    #pragma unroll
    for (int off = 32; off > 0; off >>= 1) {
        #pragma unroll
        for (int slot = 0; slot < 4; ++slot) {
            s[slot]  += __shfl_down(s[slot],  off, 64);
            kc[slot] += __shfl_down(kc[slot], off, 64);
        }
    }

    __shared__ double sh[4][8];
    const int waveInBlk = threadIdx.x >> 6;
    const int lane = threadIdx.x & 63;
    if (lane == 0) {
        #pragma unroll
        for (int slot = 0; slot < 4; ++slot) {
            sh[waveInBlk][slot]     = s[slot];
            sh[waveInBlk][4 + slot] = kc[slot];
        }
    }
    __syncthreads();
    if (threadIdx.x == 0) {
        double fs[4], fk[4];
        #pragma unroll
        for (int slot = 0; slot < 4; ++slot) {
            fs[slot] = sh[0][slot] + sh[1][slot] + sh[2][slot] + sh[3][slot];
            fk[slot] = sh[0][4+slot] + sh[1][4+slot] + sh[2][4+slot] + sh[3][4+slot];
        }
        float total = 0.0f;
        const float n = (float)N;
        for (int m = 0; m < 2; ++m) {
            const float nu = (float)fk[2 * m + 0];
            const float nc = (float)fk[2 * m + 1];
            const float us = (float)fs[2 * m + 0];
            const float cs = (float)fs[2 * m + 1];
            const float uncen_loss = -us / fmaxf(1.0f, nu);
            const float cen_loss   = -cs / fmaxf(1.0f, nc);
            total += (nu / n) * uncen_loss + (nc / n) * cen_loss * 0.5f;
        }
        out[0] = total;
    }
}

extern "C" void kernel_launch(void* const* d_in, const int* in_sizes, int n_in,
                              void* d_out, int out_size, void* d_ws, size_t ws_size,
                              hipStream_t stream)
{
    const float* preds = (const float*)d_in[0];
    const int*   labs  = (const int*)d_in[1];
    const int*   cen   = (const int*)d_in[2];
    float* out = (float*)d_out;

    const long long N = (long long)(in_sizes[1] / 2);   // labs flat = 2*N; B=100 hardcoded

    double*       bsums = (double*)d_ws;
    unsigned int* bcnts = (unsigned int*)((char*)d_ws + (size_t)4 * NBLK * sizeof(double));

    hsl_main<<<NBLK, 256, 0, stream>>>(preds, labs, cen, bsums, bcnts, N);
    hsl_final<<<1, 256, 0, stream>>>(bsums, bcnts, out, N, NBLK);
}